// Round 9
// baseline (296.862 us; speedup 1.0000x reference)
//
#include <hip/hip_runtime.h>
#include <stdint.h>

// MultiHeadAttention: B=8, N=1024 (32x32 tokens), E=1024, H=16, D=64.
// Pipeline: prep(cvt x/wqkv/wout + compact bias table) -> gemm_qkv -> attn -> gemm_out.
// All GEMM-shaped compute on v_mfma_f32_16x16x32_bf16 (fp32 accum).
// Fragment maps (learn_hip m89/m91/m120):
//   A: lane holds A[m=lane&15][k=8*(lane>>4)+t]
//   B: lane holds B[k=8*(lane>>4)+t][n=lane&15]
//   C/D: col=lane&15, row=4*(lane>>4)+reg
// R16: drop K/V LDS staging entirely. Analysis: K-LDS had ZERO cross-wave
// reuse (each wave reads only its own 32 rows) and V likewise (own
// j-window) -> LDS was a pure layout device, and the per-js
// barrier+vmcnt(0) drain cycle it forces is the invariant across all
// ~69-70us attn variants (R9/R15). Fragments now load DIRECT global->VGPR:
//   K: 16B at kb[(js*128+w*32+rt*16+col)*64 + ch*8]  (16 rows x 64B, coalesced)
//   V: 8B at vb[d*1024+js*128+32w+4qd] (+16)         (4-lane 32B segs, L2-hit)
// Q stays in 8KB sQ (one prologue barrier); per-js sQ reads protected from
// loop-invariant hoisting (would recreate the 32-reg spill) by an opaque
// asm-laundered offset. ZERO barriers in the main loop -> waves fully
// independent, loads of js+1 overlap compute of js. LDS 32KB.
// Structure from R12/R15: P in registers via PV k-order bijection k=8qd+t
// <-> j=(t<4?4qd+t:16+4qd+(t-4)); per-wave j-partial O[64x64]; epilogue
// cross-wave reduce (literal-static oacc indices); f32 VALU rowsums.
// R11 kept: gemm launch_bounds(256,3) [-14us], Q pre-scale 0.125*LOG2E,
// bias as MFMA C-init, setprio, compact bf16 bias table (1MB),
// +0x8000+perm pack.

#define LOG2E 1.4426950408889634f
#define QSCL 0.18033688011112042f  // 0.125 * LOG2E

typedef __attribute__((ext_vector_type(8))) short short8;
typedef __attribute__((ext_vector_type(4))) short short4v;
typedef __attribute__((ext_vector_type(4))) float floatx4;
typedef __attribute__((ext_vector_type(2))) unsigned int uint2v;
typedef __attribute__((ext_vector_type(4))) unsigned int uint4v;

__device__ __forceinline__ short f2bf(float f) {  // RNE, matches HW/numpy
  uint32_t u = __builtin_bit_cast(uint32_t, f);
  u = (u + 0x7FFFu + ((u >> 16) & 1u)) >> 16;
  return (short)(uint16_t)u;
}
__device__ __forceinline__ float bf2f(short s) {
  uint32_t u = ((uint32_t)(uint16_t)s) << 16;
  return __builtin_bit_cast(float, u);
}
__device__ __forceinline__ float fast_exp2(float x) {
#if __has_builtin(__builtin_amdgcn_exp2f)
  return __builtin_amdgcn_exp2f(x);
#else
  return exp2f(x);
#endif
}

__device__ __forceinline__ void gload_lds16(const short* g, short* l) {
  __builtin_amdgcn_global_load_lds(
      (const __attribute__((address_space(1))) void*)g,
      (__attribute__((address_space(3))) void*)l, 16, 0, 0);
}

// ---------------- fused prep: fp32->bf16 converts + compact bias table ----
// blocks [0,8192): x ; [8192,11264): w_qkv ; [11264,12288): w_out ;
// [12288,13312): bias tiles.
// Bias table T[h][dra][ap][bp][lane][r] = biases[h][dra*32 + |(16ap+4qd+r) -
// (16bp+col)|] * LOG2E (bf16, C-fragment order -> usable as MFMA C-init after
// bf2f), tile = ((h*32+dra)*2+ap)*2+bp. Valid because with RES=32: for
// j=32*ar+16*ap+4qd+r, rj=ar and cj=16ap+4qd+r exactly (no carry).
__global__ void prep(const float* __restrict__ x, const float* __restrict__ wqkv,
                     const float* __restrict__ wout, const float* __restrict__ biases,
                     short* __restrict__ xb, short* __restrict__ wqkvb,
                     short* __restrict__ woutb, short* __restrict__ biast) {
  int blk = blockIdx.x, tid = threadIdx.x;
  if (blk < 12288) {
    const float* src;
    short* dst;
    int i;
    if (blk < 8192) { src = x; dst = xb; i = blk * 256 + tid; }
    else if (blk < 11264) { src = wqkv; dst = wqkvb; i = (blk - 8192) * 256 + tid; }
    else { src = wout; dst = woutb; i = (blk - 11264) * 256 + tid; }
    float4 f = ((const float4*)src)[i];
    short4v o;
    o.x = f2bf(f.x); o.y = f2bf(f.y); o.z = f2bf(f.z); o.w = f2bf(f.w);
    ((short4v*)dst)[i] = o;
  } else {
    int tile = (blk - 12288) * 4 + (tid >> 6);  // [0, 4096)
    int lane = tid & 63, qd = lane >> 4, col = lane & 15;
    int bp = tile & 1, ap = (tile >> 1) & 1, dra = (tile >> 2) & 31, h = tile >> 7;
    int ci = 16 * bp + col;
    short4v o;
#pragma unroll
    for (int r = 0; r < 4; r++) {
      int cj = 16 * ap + 4 * qd + r;
      int dc = cj - ci; if (dc < 0) dc = -dc;
      o[r] = f2bf(biases[h * 1024 + dra * 32 + dc] * LOG2E);
    }
    *(short4v*)&biast[(size_t)tile * 256 + lane * 4] = o;
  }
}

// ---------------- 128x128 tile GEMM, C = A @ Bt^T ------------------
// A [M][1024] bf16 row-major, Bt [N][1024] bf16 row-major (= B transposed).
// MODE 0: QKV epilogue (scatter to q,k [bh][n][64] and vt [bh][64][n], bf16;
//         Q pre-scaled by 0.125*LOG2E so attn softmax is exp2(S+bias) direct)
// MODE 1: out-proj epilogue (add bvec, fp32 store)
// launch_bounds (256,3): cap VGPR ~170 -> 3 resident blocks/CU (m97-class
// TLP); proven -14us in R11.
template <int MODE>
__global__ __launch_bounds__(256, 3) void gemm_bt(
    const short* __restrict__ A, const short* __restrict__ Bt,
    short* __restrict__ qo, short* __restrict__ ko, short* __restrict__ vto,
    const float* __restrict__ bvec, float* __restrict__ outf) {
  __shared__ __align__(16) short sA[128 * 64];
  __shared__ __align__(16) short sB[128 * 64];
  const int tid = threadIdx.x;
  const int w = tid >> 6, lane = tid & 63;
  const int wr = w >> 1, wc = w & 1;
  const int bm = blockIdx.y, bn = blockIdx.x;
  const int qd = lane >> 4, col = lane & 15;

  floatx4 acc[4][4] = {};
  const int rowA0 = bm * 128, rowB0 = bn * 128;
  const int ciw = w * 256;

  for (int kk = 0; kk < 1024; kk += 64) {
    __syncthreads();
#pragma unroll
    for (int n = 0; n < 4; n++) {
      int ci = ciw + n * 64 + lane;
      int r = ci >> 3, c = (ci & 7) ^ (r & 7);
      gload_lds16(A + (size_t)(rowA0 + r) * 1024 + kk + c * 8, &sA[ci * 8]);
    }
#pragma unroll
    for (int n = 0; n < 4; n++) {
      int ci = ciw + n * 64 + lane;
      int r = ci >> 3, c = (ci & 7) ^ (r & 7);
      gload_lds16(Bt + (size_t)(rowB0 + r) * 1024 + kk + c * 8, &sB[ci * 8]);
    }
    __syncthreads();

#pragma unroll
    for (int ks = 0; ks < 2; ks++) {
      const int ch = qd + ks * 4;
      short8 af[4], bff[4];
#pragma unroll
      for (int rt = 0; rt < 4; rt++) {
        int r = wr * 64 + rt * 16 + col;
        af[rt] = *(const short8*)&sA[r * 64 + ((ch ^ (r & 7)) << 3)];
      }
#pragma unroll
      for (int ct = 0; ct < 4; ct++) {
        int r = wc * 64 + ct * 16 + col;
        bff[ct] = *(const short8*)&sB[r * 64 + ((ch ^ (r & 7)) << 3)];
      }
#pragma unroll
      for (int rt = 0; rt < 4; rt++)
#pragma unroll
        for (int ct = 0; ct < 4; ct++)
          acc[rt][ct] = __builtin_amdgcn_mfma_f32_16x16x32_bf16(af[rt], bff[ct], acc[rt][ct], 0, 0, 0);
    }
  }

  if (MODE == 0) {
    if (bn >= 16) {
      // V region (block-uniform): pack 4 consecutive n into b64 scatters
#pragma unroll
      for (int rt = 0; rt < 4; rt++) {
#pragma unroll
        for (int ct = 0; ct < 4; ct++) {
          int Cg = bn * 128 + wc * 64 + ct * 16 + col;
          int e = Cg & 1023, h = e >> 6, dd = e & 63;
          short4v pv;
#pragma unroll
          for (int r = 0; r < 4; r++) pv[r] = f2bf(acc[rt][ct][r]);
          int R0 = bm * 128 + wr * 64 + rt * 16 + qd * 4;
          int b = R0 >> 10, n0 = R0 & 1023;
          int bh = b * 16 + h;
          *(short4v*)&vto[((size_t)bh * 64 + dd) * 1024 + n0] = pv;
        }
      }
    } else {
#pragma unroll
      for (int rt = 0; rt < 4; rt++) {
#pragma unroll
        for (int ct = 0; ct < 4; ct++) {
          int Cg = bn * 128 + wc * 64 + ct * 16 + col;
          int which = Cg >> 10, e = Cg & 1023, h = e >> 6, dd = e & 63;
#pragma unroll
          for (int r = 0; r < 4; r++) {
            int R = bm * 128 + wr * 64 + rt * 16 + qd * 4 + r;
            int b = R >> 10, n = R & 1023;
            int bh = b * 16 + h;
            float av = acc[rt][ct][r];
            if (which == 0) av *= QSCL;  // fold softmax scale*log2e into Q
            short v = f2bf(av);
            if (which == 0)
              qo[((size_t)bh * 1024 + n) * 64 + dd] = v;
            else
              ko[((size_t)bh * 1024 + n) * 64 + dd] = v;
          }
        }
      }
    }
  } else {
#pragma unroll
    for (int rt = 0; rt < 4; rt++)
#pragma unroll
      for (int ct = 0; ct < 4; ct++) {
        int Cg = bn * 128 + wc * 64 + ct * 16 + col;
        float bo = bvec[Cg];
#pragma unroll
        for (int r = 0; r < 4; r++) {
          int R = bm * 128 + wr * 64 + rt * 16 + qd * 4 + r;
          outf[(size_t)R * 1024 + Cg] = acc[rt][ct][r] + bo;
        }
      }
  }
}

// ---------------- fused attention (flash-style, no max: logits bounded) ----
// grid.x = bh (128), grid.y = qt (16). Per block: Q-tile 64 rows; 8 K/V tiles
// of 128. S^T = K Q^T (j rows, i cols). K and V fragments load DIRECT from
// global (no LDS, no barriers in the js loop); Q B-frags read per-ks from
// sQ (8KB, XOR-8; anti-hoist laundered offset). Bias as MFMA C-init. P in
// registers via PV k-order bijection k=8qd+t <-> j=(t<4?4qd+t:16+4qd+(t-4))
// within the wave's 32-j slice; per-wave j-partial O[64x64]; epilogue
// cross-wave reduce (literal-static oacc indices). LDS 32KB (sQ + fs).
__global__ __launch_bounds__(256, 3) void attn_fused(
    const short* __restrict__ q, const short* __restrict__ k,
    const short* __restrict__ vt, const short* __restrict__ biast,
    short* __restrict__ ao) {
  __shared__ __align__(16) short smem[16384];  // 32KB: sQ (8KB) then fs epilogue
  short* sQ = smem;  // [64][64] bf16, XOR-8
  const int tid = threadIdx.x, w = tid >> 6, lane = tid & 63;
  const int bh = blockIdx.x, qt = blockIdx.y;
  const int h = bh & 15;
  const int qd = lane >> 4, col = lane & 15;
  const short* qb = q + (size_t)bh * 65536;
  const short* kb = k + (size_t)bh * 65536;
  const short* vb = vt + (size_t)bh * 65536;

  // prologue: stage Q tile (64 rows at qt*64) into sQ, XOR-8
#pragma unroll
  for (int n = 0; n < 2; n++) {
    int ci = w * 128 + n * 64 + lane;
    int r = ci >> 3, c = (ci & 7) ^ (r & 7);
    gload_lds16(qb + (size_t)(qt * 64 + r) * 64 + c * 8, &sQ[ci * 8]);
  }
  __syncthreads();  // Q staged (sole pre-epilogue barrier)

  floatx4 oacc[4][4] = {};  // [i-tile][d-tile], j-partial over this wave
  float rs[4] = {0.f, 0.f, 0.f, 0.f};  // [i-tile] partial rowsum, i=16ct+col

  for (int js = 0; js < 8; js++) {
    // anti-hoist launder: compiler cannot prove qoff==0 -> sQ reads stay
    // inside the loop (hoisting 16 short8 = 32 VGPR would spill oacc).
    int qoff = 0;
    asm volatile("" : "+v"(qoff));
    const short* sQp = sQ + qoff;

    // S^T tiles for wave's j-slice [32w,32w+32): rt=0 -> j 0..15, rt=1 -> 16..31
    uint32_t pw[4][4];  // [i-tile ct][word] packed bf16 P, A-frag order
#pragma unroll
    for (int rt = 0; rt < 2; rt++) {
      const int a = js * 8 + w * 2 + rt;  // global j-tile
      const int ar = a >> 1, ap = a & 1;
      short4v bfrag[4];
#pragma unroll
      for (int ct = 0; ct < 4; ct++) {
        int b = qt * 4 + ct;  // global i-tile
        int dra = ar - (b >> 1); if (dra < 0) dra = -dra;
        int tile = ((h * 32 + dra) * 2 + ap) * 2 + (b & 1);
        bfrag[ct] = *(const short4v*)&biast[(size_t)tile * 256 + lane * 4];
      }
      // K A-frags DIRECT from global: row js*128 + w*32 + rt*16 + col,
      // chunk ch elements [ch*8, ch*8+8). Wave = 16 rows x 64B, coalesced.
      const short* krow = kb + (size_t)(js * 128 + w * 32 + rt * 16 + col) * 64;
      short8 ak0 = *(const short8*)(krow + qd * 8);        // ch = qd
      short8 ak1 = *(const short8*)(krow + qd * 8 + 32);   // ch = qd+4
      floatx4 sacc[4];
#pragma unroll
      for (int ct = 0; ct < 4; ct++) {  // bias C-init
        sacc[ct][0] = bf2f(bfrag[ct][0]);
        sacc[ct][1] = bf2f(bfrag[ct][1]);
        sacc[ct][2] = bf2f(bfrag[ct][2]);
        sacc[ct][3] = bf2f(bfrag[ct][3]);
      }
      __builtin_amdgcn_s_setprio(1);
#pragma unroll
      for (int ks = 0; ks < 2; ks++) {
        const int ch = qd + ks * 4;
        short8 ak = (ks == 0) ? ak0 : ak1;
        short8 bqf[4];  // transient Q B-frags from sQ (16 VGPR)
#pragma unroll
        for (int ct = 0; ct < 4; ct++) {
          int r2 = ct * 16 + col;
          bqf[ct] = *(const short8*)&sQp[r2 * 64 + ((ch ^ (r2 & 7)) << 3)];
        }
#pragma unroll
        for (int ct = 0; ct < 4; ct++)
          sacc[ct] = __builtin_amdgcn_mfma_f32_16x16x32_bf16(ak, bqf[ct], sacc[ct], 0, 0, 0);
      }
      __builtin_amdgcn_s_setprio(0);
#pragma unroll
      for (int ct = 0; ct < 4; ct++) {
        float e0 = fast_exp2(sacc[ct][0]);
        float e1 = fast_exp2(sacc[ct][1]);
        float e2 = fast_exp2(sacc[ct][2]);
        float e3 = fast_exp2(sacc[ct][3]);
        rs[ct] += (e0 + e1) + (e2 + e3);
        uint32_t u0 = __builtin_bit_cast(uint32_t, e0) + 0x8000u;
        uint32_t u1 = __builtin_bit_cast(uint32_t, e1) + 0x8000u;
        uint32_t u2 = __builtin_bit_cast(uint32_t, e2) + 0x8000u;
        uint32_t u3 = __builtin_bit_cast(uint32_t, e3) + 0x8000u;
        pw[ct][2 * rt + 0] = __builtin_amdgcn_perm(u1, u0, 0x07060302u);  // [bf(e1):bf(e0)]
        pw[ct][2 * rt + 1] = __builtin_amdgcn_perm(u3, u2, 0x07060302u);  // [bf(e3):bf(e2)]
      }
    }

    // PV: O[i][d] += P[i][j-slice] V[j-slice][d]; k-order j(k)=
    // (k&7)<4 ? 4(k>>3)+(k&3) : 16+4(k>>3)+(k&3). A-frag = pw; B-frag
    // DIRECT from global vt: row d, 4 elems at j0=32w+4qd and j0+16.
    short8 pa[4], bv[4];
#pragma unroll
    for (int ct = 0; ct < 4; ct++)
      pa[ct] = __builtin_bit_cast(short8, (uint4v){pw[ct][0], pw[ct][1], pw[ct][2], pw[ct][3]});
#pragma unroll
    for (int ct = 0; ct < 4; ct++) {
      const short* vrow = vb + (size_t)(ct * 16 + col) * 1024 + js * 128 + 32 * w + 4 * qd;
      short4v lo4 = *(const short4v*)vrow;         // j0
      short4v hi4 = *(const short4v*)(vrow + 16);  // j0 + 16
      bv[ct] = __builtin_shufflevector(lo4, hi4, 0, 1, 2, 3, 4, 5, 6, 7);
    }
    __builtin_amdgcn_s_setprio(1);
#pragma unroll
    for (int ci2 = 0; ci2 < 4; ci2++)
#pragma unroll
      for (int cd = 0; cd < 4; cd++)
        oacc[ci2][cd] = __builtin_amdgcn_mfma_f32_16x16x32_bf16(pa[ci2], bv[cd], oacc[ci2][cd], 0, 0, 0);
    __builtin_amdgcn_s_setprio(0);
  }

  __syncthreads();  // all waves done with sQ -> fs may overwrite it

  // ---------------- epilogue: cross-wave reduce + normalize ----------------
  float* fs = (float*)smem;  // 8192 f32 = 32KB scratch
  // rowsum partials: rsb[(w*4+qd)*64 + i], i = 16ct+col
#pragma unroll
  for (int ct = 0; ct < 4; ct++)
    fs[(w * 4 + qd) * 64 + 16 * ct + col] = rs[ct];
  __syncthreads();  // E1
  {
    float tot = 0.f;
#pragma unroll
    for (int kk = 0; kk < 16; kk++) tot += fs[kk * 64 + lane];
    fs[1024 + lane] = 1.0f / tot;  // rsbuf2: inv rowsum for i=lane
  }
  __syncthreads();  // E2
  float myinv[8];  // w<2 only: inv for i = 16*(w*2+t2)+4qd+r
  if (w < 2) {
#pragma unroll
    for (int t2 = 0; t2 < 2; t2++)
#pragma unroll
      for (int r = 0; r < 4; r++)
        myinv[t2 * 4 + r] = fs[1024 + (w * 2 + t2) * 16 + 4 * qd + r];
  }
  __syncthreads();  // E3: rsbuf reads done -> obuf may overwrite
  if (w >= 2) {     // round 1: waves 2,3 publish full oacc (16KB each)
    float* ob = fs + (w - 2) * 4096;
#pragma unroll
    for (int ci2 = 0; ci2 < 4; ci2++)
#pragma unroll
      for (int cd = 0; cd < 4; cd++)
        *(floatx4*)&ob[((ci2 * 4 + cd) * 64 + lane) * 4] = oacc[ci2][cd];
  }
  __syncthreads();  // E4
  if (w < 2) {      // waves 0,1 absorb partners 2,3
    float* ob = fs + w * 4096;
#pragma unroll
    for (int ci2 = 0; ci2 < 4; ci2++)
#pragma unroll
      for (int cd = 0; cd < 4; cd++)
        oacc[ci2][cd] += *(const floatx4*)&ob[((ci2 * 4 + cd) * 64 + lane) * 4];
  }
  __syncthreads();  // E5
  if (w == 1) {     // round 2: w1 publishes i-tiles {0,1} -> fs[0:2048)
#pragma unroll
    for (int t2 = 0; t2 < 2; t2++)
#pragma unroll
      for (int cd = 0; cd < 4; cd++)
        *(floatx4*)&fs[((t2 * 4 + cd) * 64 + lane) * 4] = oacc[t2][cd];
  }
  if (w == 0) {     // w0 publishes i-tiles {2,3} -> fs[2048:4096)
#pragma unroll
    for (int t2 = 0; t2 < 2; t2++)
#pragma unroll
      for (int cd = 0; cd < 4; cd++)
        *(floatx4*)&fs[2048 + ((t2 * 4 + cd) * 64 + lane) * 4] = oacc[2 + t2][cd];
  }
  __syncthreads();  // E6
  // finalize: duplicated wave-uniform branches; all oacc indices literal.
  const int b = bh >> 4;
  if (w == 0) {
    // w0 finalizes i-tiles {0,1}: own oacc[0..1] + w1's partial at fs[0:2048)
#pragma unroll
    for (int t2 = 0; t2 < 2; t2++) {
#pragma unroll
      for (int cd = 0; cd < 4; cd++) {
        floatx4 p = *(const floatx4*)&fs[((t2 * 4 + cd) * 64 + lane) * 4];
        floatx4 o = (t2 == 0 ? oacc[0][cd] : oacc[1][cd]);
        o += p;
#pragma unroll
        for (int r = 0; r < 4; r++) {
          int i = 16 * t2 + 4 * qd + r;
          int n = qt * 64 + i;
          int dd = cd * 16 + col;
          ao[(((size_t)b * 1024 + n) << 10) + h * 64 + dd] = f2bf(o[r] * myinv[t2 * 4 + r]);
        }
      }
    }
  } else if (w == 1) {
    // w1 finalizes i-tiles {2,3}: own oacc[2..3] + w0's partial at fs[2048:4096)
#pragma unroll
    for (int t2 = 0; t2 < 2; t2++) {
#pragma unroll
      for (int cd = 0; cd < 4; cd++) {
        floatx4 p = *(const floatx4*)&fs[2048 + ((t2 * 4 + cd) * 64 + lane) * 4];
        floatx4 o = (t2 == 0 ? oacc[2][cd] : oacc[3][cd]);
        o += p;
#pragma unroll
        for (int r = 0; r < 4; r++) {
          int i = 16 * (2 + t2) + 4 * qd + r;
          int n = qt * 64 + i;
          int dd = cd * 16 + col;
          ao[(((size_t)b * 1024 + n) << 10) + h * 64 + dd] = f2bf(o[r] * myinv[t2 * 4 + r]);
        }
      }
    }
  }
}

// -------------------------------------------------------------------
extern "C" void kernel_launch(void* const* d_in, const int* in_sizes, int n_in,
                              void* d_out, int out_size, void* d_ws, size_t ws_size,
                              hipStream_t stream) {
  const float* x = (const float*)d_in[0];       // [8,1024,1024]
  const float* w_qkv = (const float*)d_in[1];   // [3072,1024]
  const float* biases = (const float*)d_in[2];  // [16,1024]
  // d_in[3] bias_idxs unused: index formula is closed-form
  const float* w_out = (const float*)d_in[4];   // [1024,1024]
  const float* b_out = (const float*)d_in[5];   // [1024]
  float* out = (float*)d_out;

  char* ws = (char*)d_ws;
  short* xb    = (short*)(ws + 0);          // 16 MB  [8192][1024]
  short* wqkvb = (short*)(ws + 16777216);   // 6 MB   [3072][1024]
  short* woutb = (short*)(ws + 23068672);   // 2 MB   [1024][1024]
  short* qb    = (short*)(ws + 25165824);   // 16 MB  [128 bh][1024][64]
  short* kb    = (short*)(ws + 41943040);   // 16 MB
  short* vtb   = (short*)(ws + 58720256);   // 16 MB  [128 bh][64][1024]
  short* aob   = (short*)(ws + 75497472);   // 16 MB  [8192][1024]
  short* biast = (short*)(ws + 92274688);   // 1 MB   [16][32][2][2][64][4] bf16

  prep<<<13312, 256, 0, stream>>>(x, w_qkv, w_out, biases, xb, wqkvb, woutb, biast);
  gemm_bt<0><<<dim3(24, 64), 256, 0, stream>>>(xb, wqkvb, qb, kb, vtb, nullptr, nullptr);
  attn_fused<<<dim3(128, 16), 256, 0, stream>>>(qb, kb, vtb, biast, aob);
  gemm_bt<1><<<dim3(8, 64), 256, 0, stream>>>(aob, woutb, nullptr, nullptr, nullptr, b_out, out);
}

// Round 10
// 238.898 us; speedup vs baseline: 1.2426x; 1.2426x over previous
//
#include <hip/hip_runtime.h>
#include <stdint.h>

// MultiHeadAttention: B=8, N=1024 (32x32 tokens), E=1024, H=16, D=64.
// Pipeline: prep(cvt x/wqkv/wout + compact bias table) -> gemm_qkv -> attn -> gemm_out.
// All GEMM-shaped compute on v_mfma_f32_16x16x32_bf16 (fp32 accum).
// Fragment maps (learn_hip m89/m91/m120):
//   A: lane holds A[m=lane&15][k=8*(lane>>4)+t]
//   B: lane holds B[k=8*(lane>>4)+t][n=lane&15]
//   C/D: col=lane&15, row=4*(lane>>4)+reg
// R17: (a) REVERT attn to R15 body (R16's direct-global fragments were
// latency-exposed: every util counter dropped, 115us; LDS-DMA staging's
// fire-and-forget + TLP was the right structure all along — R9/R15 both 69us).
// (b) XCD L2-locality swizzle (T1) for attn: 1-D grid, sid=(id&7)*256+(id>>3)
// (bijective, 2048%8==0) -> XCD i gets contiguous bh range [16i,16i+16);
// its 16-qt-reuse K/V working set (~4MB) fits the per-XCD 4MB L2. Attacks
// the latency bound (HBM-miss ~900cy -> L2-hit ~200cy) with zero numerics
// risk.
// R15 kept: sQ 8KB (per-ks Q B-frags, no 32-reg hoist -> no spill at
// (256,3)), K/V LDS staging via global_load_lds, 2 barriers/js, P in
// registers via PV k-order bijection k=8qd+t <-> j=(t<4?4qd+t:16+4qd+(t-4)),
// per-wave j-partial O[64x64], epilogue cross-wave reduce (literal-static
// oacc indices), f32 VALU rowsums.
// R11 kept: gemm launch_bounds(256,3) [-14us], Q pre-scale 0.125*LOG2E,
// bias as MFMA C-init, setprio, compact bf16 bias table (1MB),
// +0x8000+perm pack.

#define LOG2E 1.4426950408889634f
#define QSCL 0.18033688011112042f  // 0.125 * LOG2E

typedef __attribute__((ext_vector_type(8))) short short8;
typedef __attribute__((ext_vector_type(4))) short short4v;
typedef __attribute__((ext_vector_type(4))) float floatx4;
typedef __attribute__((ext_vector_type(2))) unsigned int uint2v;
typedef __attribute__((ext_vector_type(4))) unsigned int uint4v;

__device__ __forceinline__ short f2bf(float f) {  // RNE, matches HW/numpy
  uint32_t u = __builtin_bit_cast(uint32_t, f);
  u = (u + 0x7FFFu + ((u >> 16) & 1u)) >> 16;
  return (short)(uint16_t)u;
}
__device__ __forceinline__ float bf2f(short s) {
  uint32_t u = ((uint32_t)(uint16_t)s) << 16;
  return __builtin_bit_cast(float, u);
}
__device__ __forceinline__ float fast_exp2(float x) {
#if __has_builtin(__builtin_amdgcn_exp2f)
  return __builtin_amdgcn_exp2f(x);
#else
  return exp2f(x);
#endif
}

__device__ __forceinline__ void gload_lds16(const short* g, short* l) {
  __builtin_amdgcn_global_load_lds(
      (const __attribute__((address_space(1))) void*)g,
      (__attribute__((address_space(3))) void*)l, 16, 0, 0);
}

// ---------------- fused prep: fp32->bf16 converts + compact bias table ----
// blocks [0,8192): x ; [8192,11264): w_qkv ; [11264,12288): w_out ;
// [12288,13312): bias tiles.
// Bias table T[h][dra][ap][bp][lane][r] = biases[h][dra*32 + |(16ap+4qd+r) -
// (16bp+col)|] * LOG2E (bf16, C-fragment order -> usable as MFMA C-init after
// bf2f), tile = ((h*32+dra)*2+ap)*2+bp. Valid because with RES=32: for
// j=32*ar+16*ap+4qd+r, rj=ar and cj=16ap+4qd+r exactly (no carry).
__global__ void prep(const float* __restrict__ x, const float* __restrict__ wqkv,
                     const float* __restrict__ wout, const float* __restrict__ biases,
                     short* __restrict__ xb, short* __restrict__ wqkvb,
                     short* __restrict__ woutb, short* __restrict__ biast) {
  int blk = blockIdx.x, tid = threadIdx.x;
  if (blk < 12288) {
    const float* src;
    short* dst;
    int i;
    if (blk < 8192) { src = x; dst = xb; i = blk * 256 + tid; }
    else if (blk < 11264) { src = wqkv; dst = wqkvb; i = (blk - 8192) * 256 + tid; }
    else { src = wout; dst = woutb; i = (blk - 11264) * 256 + tid; }
    float4 f = ((const float4*)src)[i];
    short4v o;
    o.x = f2bf(f.x); o.y = f2bf(f.y); o.z = f2bf(f.z); o.w = f2bf(f.w);
    ((short4v*)dst)[i] = o;
  } else {
    int tile = (blk - 12288) * 4 + (tid >> 6);  // [0, 4096)
    int lane = tid & 63, qd = lane >> 4, col = lane & 15;
    int bp = tile & 1, ap = (tile >> 1) & 1, dra = (tile >> 2) & 31, h = tile >> 7;
    int ci = 16 * bp + col;
    short4v o;
#pragma unroll
    for (int r = 0; r < 4; r++) {
      int cj = 16 * ap + 4 * qd + r;
      int dc = cj - ci; if (dc < 0) dc = -dc;
      o[r] = f2bf(biases[h * 1024 + dra * 32 + dc] * LOG2E);
    }
    *(short4v*)&biast[(size_t)tile * 256 + lane * 4] = o;
  }
}

// ---------------- 128x128 tile GEMM, C = A @ Bt^T ------------------
// A [M][1024] bf16 row-major, Bt [N][1024] bf16 row-major (= B transposed).
// MODE 0: QKV epilogue (scatter to q,k [bh][n][64] and vt [bh][64][n], bf16;
//         Q pre-scaled by 0.125*LOG2E so attn softmax is exp2(S+bias) direct)
// MODE 1: out-proj epilogue (add bvec, fp32 store)
// launch_bounds (256,3): cap VGPR ~170 -> 3 resident blocks/CU (m97-class
// TLP); proven -14us in R11.
template <int MODE>
__global__ __launch_bounds__(256, 3) void gemm_bt(
    const short* __restrict__ A, const short* __restrict__ Bt,
    short* __restrict__ qo, short* __restrict__ ko, short* __restrict__ vto,
    const float* __restrict__ bvec, float* __restrict__ outf) {
  __shared__ __align__(16) short sA[128 * 64];
  __shared__ __align__(16) short sB[128 * 64];
  const int tid = threadIdx.x;
  const int w = tid >> 6, lane = tid & 63;
  const int wr = w >> 1, wc = w & 1;
  const int bm = blockIdx.y, bn = blockIdx.x;
  const int qd = lane >> 4, col = lane & 15;

  floatx4 acc[4][4] = {};
  const int rowA0 = bm * 128, rowB0 = bn * 128;
  const int ciw = w * 256;

  for (int kk = 0; kk < 1024; kk += 64) {
    __syncthreads();
#pragma unroll
    for (int n = 0; n < 4; n++) {
      int ci = ciw + n * 64 + lane;
      int r = ci >> 3, c = (ci & 7) ^ (r & 7);
      gload_lds16(A + (size_t)(rowA0 + r) * 1024 + kk + c * 8, &sA[ci * 8]);
    }
#pragma unroll
    for (int n = 0; n < 4; n++) {
      int ci = ciw + n * 64 + lane;
      int r = ci >> 3, c = (ci & 7) ^ (r & 7);
      gload_lds16(Bt + (size_t)(rowB0 + r) * 1024 + kk + c * 8, &sB[ci * 8]);
    }
    __syncthreads();

#pragma unroll
    for (int ks = 0; ks < 2; ks++) {
      const int ch = qd + ks * 4;
      short8 af[4], bff[4];
#pragma unroll
      for (int rt = 0; rt < 4; rt++) {
        int r = wr * 64 + rt * 16 + col;
        af[rt] = *(const short8*)&sA[r * 64 + ((ch ^ (r & 7)) << 3)];
      }
#pragma unroll
      for (int ct = 0; ct < 4; ct++) {
        int r = wc * 64 + ct * 16 + col;
        bff[ct] = *(const short8*)&sB[r * 64 + ((ch ^ (r & 7)) << 3)];
      }
#pragma unroll
      for (int rt = 0; rt < 4; rt++)
#pragma unroll
        for (int ct = 0; ct < 4; ct++)
          acc[rt][ct] = __builtin_amdgcn_mfma_f32_16x16x32_bf16(af[rt], bff[ct], acc[rt][ct], 0, 0, 0);
    }
  }

  if (MODE == 0) {
    if (bn >= 16) {
      // V region (block-uniform): pack 4 consecutive n into b64 scatters
#pragma unroll
      for (int rt = 0; rt < 4; rt++) {
#pragma unroll
        for (int ct = 0; ct < 4; ct++) {
          int Cg = bn * 128 + wc * 64 + ct * 16 + col;
          int e = Cg & 1023, h = e >> 6, dd = e & 63;
          short4v pv;
#pragma unroll
          for (int r = 0; r < 4; r++) pv[r] = f2bf(acc[rt][ct][r]);
          int R0 = bm * 128 + wr * 64 + rt * 16 + qd * 4;
          int b = R0 >> 10, n0 = R0 & 1023;
          int bh = b * 16 + h;
          *(short4v*)&vto[((size_t)bh * 64 + dd) * 1024 + n0] = pv;
        }
      }
    } else {
#pragma unroll
      for (int rt = 0; rt < 4; rt++) {
#pragma unroll
        for (int ct = 0; ct < 4; ct++) {
          int Cg = bn * 128 + wc * 64 + ct * 16 + col;
          int which = Cg >> 10, e = Cg & 1023, h = e >> 6, dd = e & 63;
#pragma unroll
          for (int r = 0; r < 4; r++) {
            int R = bm * 128 + wr * 64 + rt * 16 + qd * 4 + r;
            int b = R >> 10, n = R & 1023;
            int bh = b * 16 + h;
            float av = acc[rt][ct][r];
            if (which == 0) av *= QSCL;  // fold softmax scale*log2e into Q
            short v = f2bf(av);
            if (which == 0)
              qo[((size_t)bh * 1024 + n) * 64 + dd] = v;
            else
              ko[((size_t)bh * 1024 + n) * 64 + dd] = v;
          }
        }
      }
    }
  } else {
#pragma unroll
    for (int rt = 0; rt < 4; rt++)
#pragma unroll
      for (int ct = 0; ct < 4; ct++) {
        int Cg = bn * 128 + wc * 64 + ct * 16 + col;
        float bo = bvec[Cg];
#pragma unroll
        for (int r = 0; r < 4; r++) {
          int R = bm * 128 + wr * 64 + rt * 16 + qd * 4 + r;
          outf[(size_t)R * 1024 + Cg] = acc[rt][ct][r] + bo;
        }
      }
  }
}

// ---------------- fused attention (flash-style, no max: logits bounded) ----
// 1-D grid 2048, XCD-swizzled: sid=(id&7)*256+(id>>3); bh=sid>>4, qt=sid&15.
// XCD i (round-robin id%8) processes contiguous bh [16i,16i+16) -> its K/V
// 16-qt reuse set (~4MB) fits the per-XCD 4MB L2.
// Per block: Q-tile 64 rows; 8 K/V tiles of 128. S^T = K Q^T (j rows, i
// cols); Q B-frags read per-ks from sQ (8KB, XOR-8) — NOT register-hoisted
// (32-reg hoist overflowed the (256,3) cap and spilled oacc). Bias as MFMA
// C-init. P in registers via PV k-order bijection k=8qd+t <->
// j=(t<4?4qd+t:16+4qd+(t-4)); per-wave j-partial O[64x64]; epilogue
// cross-wave reduce (literal-static oacc indices).
// LDS 40KB: sQ 8KB + sK 16KB (XOR-8) + sVt 16KB (XOR-16). 2 barriers/js.
__global__ __launch_bounds__(256, 3) void attn_fused(
    const short* __restrict__ q, const short* __restrict__ k,
    const short* __restrict__ vt, const short* __restrict__ biast,
    short* __restrict__ ao) {
  __shared__ __align__(16) short smem[20480];  // 40KB
  short* sQ = smem;            // [64][64] bf16, XOR-8 (4096 shorts)
  short* sK = smem + 4096;     // [128][64] bf16, XOR-8 (8192 shorts)
  short* sVt = smem + 12288;   // [64][128] bf16, XOR-16 (8192 shorts)
  const int tid = threadIdx.x, w = tid >> 6, lane = tid & 63;
  const int id = blockIdx.x;
  const int sid = (id & 7) * 256 + (id >> 3);  // XCD-chunked (bijective)
  const int bh = sid >> 4, qt = sid & 15;
  const int h = bh & 15;
  const int qd = lane >> 4, col = lane & 15;
  const short* qb = q + (size_t)bh * 65536;
  const short* kb = k + (size_t)bh * 65536;
  const short* vb = vt + (size_t)bh * 65536;
  const int ciw = w * 256;

  // prologue: issue Q-tile gloads into sQ (XOR-8); drained by js=0's B2
#pragma unroll
  for (int n = 0; n < 2; n++) {
    int ci = w * 128 + n * 64 + lane;  // [0,512) chunks of 8 shorts
    int r = ci >> 3, c = (ci & 7) ^ (r & 7);
    gload_lds16(qb + (size_t)(qt * 64 + r) * 64 + c * 8, &sQ[ci * 8]);
  }

  floatx4 oacc[4][4] = {};  // [i-tile][d-tile], j-partial over this wave
  float rs[4] = {0.f, 0.f, 0.f, 0.f};  // [i-tile] partial rowsum, i=16ct+col

  for (int js = 0; js < 8; js++) {
    // stage K tile [128][64] into sK (XOR-8), Vt tile [64][128] (XOR-16)
#pragma unroll
    for (int n = 0; n < 4; n++) {
      int ci = ciw + n * 64 + lane;
      int r = ci >> 3, c = (ci & 7) ^ (r & 7);
      gload_lds16(kb + (size_t)(js * 128 + r) * 64 + c * 8, &sK[ci * 8]);
    }
#pragma unroll
    for (int n = 0; n < 4; n++) {
      int ci = ciw + n * 64 + lane;
      int r = ci >> 4, c = (ci & 15) ^ (r & 15);
      gload_lds16(vb + (size_t)r * 1024 + js * 128 + c * 8, &sVt[ci * 8]);
    }
    __syncthreads();  // B2: staged (js=0: Q also drained)

    // S^T tiles for wave's j-slice [32w,32w+32): rt=0 -> j 0..15, rt=1 -> 16..31
    uint32_t pw[4][4];  // [i-tile ct][word] packed bf16 P, A-frag order
#pragma unroll
    for (int rt = 0; rt < 2; rt++) {
      const int a = js * 8 + w * 2 + rt;  // global j-tile
      const int ar = a >> 1, ap = a & 1;
      short4v bfrag[4];
#pragma unroll
      for (int ct = 0; ct < 4; ct++) {
        int b = qt * 4 + ct;  // global i-tile
        int dra = ar - (b >> 1); if (dra < 0) dra = -dra;
        int tile = ((h * 32 + dra) * 2 + ap) * 2 + (b & 1);
        bfrag[ct] = *(const short4v*)&biast[(size_t)tile * 256 + lane * 4];
      }
      const int r = w * 32 + rt * 16 + col;
      floatx4 sacc[4];
#pragma unroll
      for (int ct = 0; ct < 4; ct++) {  // bias C-init
        sacc[ct][0] = bf2f(bfrag[ct][0]);
        sacc[ct][1] = bf2f(bfrag[ct][1]);
        sacc[ct][2] = bf2f(bfrag[ct][2]);
        sacc[ct][3] = bf2f(bfrag[ct][3]);
      }
      __builtin_amdgcn_s_setprio(1);
#pragma unroll
      for (int ks = 0; ks < 2; ks++) {
        const int ch = qd + ks * 4;
        short8 ak = *(const short8*)&sK[r * 64 + ((ch ^ (r & 7)) << 3)];
        short8 bqf[4];  // transient Q B-frags from sQ (16 VGPR)
#pragma unroll
        for (int ct = 0; ct < 4; ct++) {
          int r2 = ct * 16 + col;
          bqf[ct] = *(const short8*)&sQ[r2 * 64 + ((ch ^ (r2 & 7)) << 3)];
        }
#pragma unroll
        for (int ct = 0; ct < 4; ct++)
          sacc[ct] = __builtin_amdgcn_mfma_f32_16x16x32_bf16(ak, bqf[ct], sacc[ct], 0, 0, 0);
      }
      __builtin_amdgcn_s_setprio(0);
#pragma unroll
      for (int ct = 0; ct < 4; ct++) {
        float e0 = fast_exp2(sacc[ct][0]);
        float e1 = fast_exp2(sacc[ct][1]);
        float e2 = fast_exp2(sacc[ct][2]);
        float e3 = fast_exp2(sacc[ct][3]);
        rs[ct] += (e0 + e1) + (e2 + e3);
        uint32_t u0 = __builtin_bit_cast(uint32_t, e0) + 0x8000u;
        uint32_t u1 = __builtin_bit_cast(uint32_t, e1) + 0x8000u;
        uint32_t u2 = __builtin_bit_cast(uint32_t, e2) + 0x8000u;
        uint32_t u3 = __builtin_bit_cast(uint32_t, e3) + 0x8000u;
        pw[ct][2 * rt + 0] = __builtin_amdgcn_perm(u1, u0, 0x07060302u);  // [bf(e1):bf(e0)]
        pw[ct][2 * rt + 1] = __builtin_amdgcn_perm(u3, u2, 0x07060302u);  // [bf(e3):bf(e2)]
      }
    }

    // PV: O[i][d] += P[i][j-slice] V[j-slice][d]; k-order j(k)=
    // (k&7)<4 ? 4(k>>3)+(k&3) : 16+4(k>>3)+(k&3). A-frag = pw; B-frag from
    // sVt: lo4 at j0=32w+4qd, hi4 at j0+16 (chunk-swizzled XOR-16 layout).
    short8 pa[4], bv[4];
#pragma unroll
    for (int ct = 0; ct < 4; ct++)
      pa[ct] = __builtin_bit_cast(short8, (uint4v){pw[ct][0], pw[ct][1], pw[ct][2], pw[ct][3]});
    const int jc0 = 4 * w + (qd >> 1), off = 4 * (qd & 1);
#pragma unroll
    for (int ct = 0; ct < 4; ct++) {
      int d = ct * 16 + col;
      short4v lo4 = *(const short4v*)&sVt[d * 128 + ((jc0 ^ (d & 15)) << 3) + off];
      short4v hi4 = *(const short4v*)&sVt[d * 128 + (((jc0 + 2) ^ (d & 15)) << 3) + off];
      bv[ct] = __builtin_shufflevector(lo4, hi4, 0, 1, 2, 3, 4, 5, 6, 7);
    }
    __builtin_amdgcn_s_setprio(1);
#pragma unroll
    for (int ci2 = 0; ci2 < 4; ci2++)
#pragma unroll
      for (int cd = 0; cd < 4; cd++)
        oacc[ci2][cd] = __builtin_amdgcn_mfma_f32_16x16x32_bf16(pa[ci2], bv[cd], oacc[ci2][cd], 0, 0, 0);
    __builtin_amdgcn_s_setprio(0);
    __syncthreads();  // B1: all sQ/sK/sVt reads done -> next js may overwrite
  }

  // ---------------- epilogue: cross-wave reduce + normalize ----------------
  float* fs = (float*)smem;  // 10240 f32 = 40KB scratch (uses 8192)
  // (loop-final barrier = all K/V reads done; smem reusable)
  // rowsum partials: rsb[(w*4+qd)*64 + i], i = 16ct+col
#pragma unroll
  for (int ct = 0; ct < 4; ct++)
    fs[(w * 4 + qd) * 64 + 16 * ct + col] = rs[ct];
  __syncthreads();  // E1
  {
    float tot = 0.f;
#pragma unroll
    for (int kk = 0; kk < 16; kk++) tot += fs[kk * 64 + lane];
    fs[1024 + lane] = 1.0f / tot;  // rsbuf2: inv rowsum for i=lane
  }
  __syncthreads();  // E2
  float myinv[8];  // w<2 only: inv for i = 16*(w*2+t2)+4qd+r
  if (w < 2) {
#pragma unroll
    for (int t2 = 0; t2 < 2; t2++)
#pragma unroll
      for (int r = 0; r < 4; r++)
        myinv[t2 * 4 + r] = fs[1024 + (w * 2 + t2) * 16 + 4 * qd + r];
  }
  __syncthreads();  // E3: rsbuf reads done -> obuf may overwrite
  if (w >= 2) {     // round 1: waves 2,3 publish full oacc (16KB each)
    float* ob = fs + (w - 2) * 4096;
#pragma unroll
    for (int ci2 = 0; ci2 < 4; ci2++)
#pragma unroll
      for (int cd = 0; cd < 4; cd++)
        *(floatx4*)&ob[((ci2 * 4 + cd) * 64 + lane) * 4] = oacc[ci2][cd];
  }
  __syncthreads();  // E4
  if (w < 2) {      // waves 0,1 absorb partners 2,3
    float* ob = fs + w * 4096;
#pragma unroll
    for (int ci2 = 0; ci2 < 4; ci2++)
#pragma unroll
      for (int cd = 0; cd < 4; cd++)
        oacc[ci2][cd] += *(const floatx4*)&ob[((ci2 * 4 + cd) * 64 + lane) * 4];
  }
  __syncthreads();  // E5
  if (w == 1) {     // round 2: w1 publishes i-tiles {0,1} -> fs[0:2048)
#pragma unroll
    for (int t2 = 0; t2 < 2; t2++)
#pragma unroll
      for (int cd = 0; cd < 4; cd++)
        *(floatx4*)&fs[((t2 * 4 + cd) * 64 + lane) * 4] = oacc[t2][cd];
  }
  if (w == 0) {     // w0 publishes i-tiles {2,3} -> fs[2048:4096)
#pragma unroll
    for (int t2 = 0; t2 < 2; t2++)
#pragma unroll
      for (int cd = 0; cd < 4; cd++)
        *(floatx4*)&fs[2048 + ((t2 * 4 + cd) * 64 + lane) * 4] = oacc[2 + t2][cd];
  }
  __syncthreads();  // E6
  // finalize: duplicated wave-uniform branches; all oacc indices literal.
  const int b = bh >> 4;
  if (w == 0) {
    // w0 finalizes i-tiles {0,1}: own oacc[0..1] + w1's partial at fs[0:2048)
#pragma unroll
    for (int t2 = 0; t2 < 2; t2++) {
#pragma unroll
      for (int cd = 0; cd < 4; cd++) {
        floatx4 p = *(const floatx4*)&fs[((t2 * 4 + cd) * 64 + lane) * 4];
        floatx4 o = (t2 == 0 ? oacc[0][cd] : oacc[1][cd]);
        o += p;
#pragma unroll
        for (int r = 0; r < 4; r++) {
          int i = 16 * t2 + 4 * qd + r;
          int n = qt * 64 + i;
          int dd = cd * 16 + col;
          ao[(((size_t)b * 1024 + n) << 10) + h * 64 + dd] = f2bf(o[r] * myinv[t2 * 4 + r]);
        }
      }
    }
  } else if (w == 1) {
    // w1 finalizes i-tiles {2,3}: own oacc[2..3] + w0's partial at fs[2048:4096)
#pragma unroll
    for (int t2 = 0; t2 < 2; t2++) {
#pragma unroll
      for (int cd = 0; cd < 4; cd++) {
        floatx4 p = *(const floatx4*)&fs[2048 + ((t2 * 4 + cd) * 64 + lane) * 4];
        floatx4 o = (t2 == 0 ? oacc[2][cd] : oacc[3][cd]);
        o += p;
#pragma unroll
        for (int r = 0; r < 4; r++) {
          int i = 16 * (2 + t2) + 4 * qd + r;
          int n = qt * 64 + i;
          int dd = cd * 16 + col;
          ao[(((size_t)b * 1024 + n) << 10) + h * 64 + dd] = f2bf(o[r] * myinv[t2 * 4 + r]);
        }
      }
    }
  }
}

// -------------------------------------------------------------------
extern "C" void kernel_launch(void* const* d_in, const int* in_sizes, int n_in,
                              void* d_out, int out_size, void* d_ws, size_t ws_size,
                              hipStream_t stream) {
  const float* x = (const float*)d_in[0];       // [8,1024,1024]
  const float* w_qkv = (const float*)d_in[1];   // [3072,1024]
  const float* biases = (const float*)d_in[2];  // [16,1024]
  // d_in[3] bias_idxs unused: index formula is closed-form
  const float* w_out = (const float*)d_in[4];   // [1024,1024]
  const float* b_out = (const float*)d_in[5];   // [1024]
  float* out = (float*)d_out;

  char* ws = (char*)d_ws;
  short* xb    = (short*)(ws + 0);          // 16 MB  [8192][1024]
  short* wqkvb = (short*)(ws + 16777216);   // 6 MB   [3072][1024]
  short* woutb = (short*)(ws + 23068672);   // 2 MB   [1024][1024]
  short* qb    = (short*)(ws + 25165824);   // 16 MB  [128 bh][1024][64]
  short* kb    = (short*)(ws + 41943040);   // 16 MB
  short* vtb   = (short*)(ws + 58720256);   // 16 MB  [128 bh][64][1024]
  short* aob   = (short*)(ws + 75497472);   // 16 MB  [8192][1024]
  short* biast = (short*)(ws + 92274688);   // 1 MB   [16][32][2][2][64][4] bf16

  prep<<<13312, 256, 0, stream>>>(x, w_qkv, w_out, biases, xb, wqkvb, woutb, biast);
  gemm_bt<0><<<dim3(24, 64), 256, 0, stream>>>(xb, wqkvb, qb, kb, vtb, nullptr, nullptr);
  attn_fused<<<2048, 256, 0, stream>>>(qb, kb, vtb, biast, aob);
  gemm_bt<1><<<dim3(8, 64), 256, 0, stream>>>(aob, woutb, nullptr, nullptr, nullptr, b_out, out);
}